// Round 7
// baseline (85.731 us; speedup 1.0000x reference)
//
#include <hip/hip_runtime.h>

// Contrast-depth loss:
//   d = out - label   (elementwise, [B,32,32] fp32)
//   loss = mean over (b, 8 neighbors, 30x30 centers) of
//          (d[y+dy][x+dx] - d[y][x])^2, centers y,x in [1,30]
//
// R7 design: global_load_lds staging (no VGPR round trip, no L1 amplification),
// triple-buffered LDS, counted s_waitcnt vmcnt(N) (never 0 mid-loop), raw
// s_barrier (no compiler vmcnt(0) drain). Proven R5 stencil + R4 reduction.

#define THREADS 256
#define NBUF 3
#define BI 2           // images per batch
#define NB 4           // batches per block -> 8 images per block

#define GLOAD_LDS(g, l) __builtin_amdgcn_global_load_lds( \
    (const __attribute__((address_space(1))) void*)(g),   \
    (__attribute__((address_space(3))) void*)(l), 16, 0, 0)

__global__ __launch_bounds__(THREADS) void cdl_fused(
    const float* __restrict__ outp,
    const float* __restrict__ labp,
    float* __restrict__ partial,
    int* __restrict__ counter,      // memset to 0 before launch
    float* __restrict__ out,
    int nimg, float inv_count)
{
    __shared__ float lds[NBUF][2][BI * 1024];   // [buf][out/label][2 img]
    __shared__ float red[4];

    const int t = threadIdx.x;
    const int lane = t & 63, wid = t >> 6;
    const int img0 = blockIdx.x * (NB * BI);

    float acc = 0.f;

    // stage batch bb into buffer bf: 4 global_load_lds per thread.
    // wave w covers floats [w*512, w*512+512) of the 2048-float batch array;
    // waves 0,1 -> image a, waves 2,3 -> image b (512-float chunks align).
    auto stage = [&](int bf, int bb) {
        const int ia = min(img0 + bb * BI,     nimg - 1);   // clamp: masked later
        const int ib = min(img0 + bb * BI + 1, nimg - 1);
        const long long g0 = (long long)(wid < 2 ? ia : ib) * 1024
                           + (wid & 1) * 512 + lane * 4;
        const float* go = outp + g0;
        const float* gl = labp + g0;
        float* lo = &lds[bf][0][wid * 512];     // wave-uniform dest
        float* ll = &lds[bf][1][wid * 512];
        GLOAD_LDS(go,       lo);
        GLOAD_LDS(go + 256, lo + 256);
        GLOAD_LDS(gl,       ll);
        GLOAD_LDS(gl + 256, ll + 256);
    };

    auto compute = [&](int bf, int bb) {
        #pragma unroll
        for (int it = 0; it < 2; ++it) {
            const int tt = it * 256 + t;
            const int tk = (tt < 450) ? tt : 0;
            const int img = tk / 225, q = tk - img * 225;
            const bool act = (tt < 450) && (img0 + bb * BI + img < nimg);
            const int qy = q / 15, qx = q - qy * 15;
            const int bw = img * 1024 + qy * 64 + qx * 2;   // even -> 8B aligned
            float dd[4][4];
            #pragma unroll
            for (int r = 0; r < 4; ++r) {
                const float2 o0 = *(const float2*)&lds[bf][0][bw + 32 * r];
                const float2 o1 = *(const float2*)&lds[bf][0][bw + 32 * r + 2];
                const float2 l0 = *(const float2*)&lds[bf][1][bw + 32 * r];
                const float2 l1 = *(const float2*)&lds[bf][1][bw + 32 * r + 2];
                dd[r][0] = o0.x - l0.x; dd[r][1] = o0.y - l0.y;
                dd[r][2] = o1.x - l1.x; dd[r][3] = o1.y - l1.y;
            }
            float sub = 0.f;
            #pragma unroll
            for (int cy = 1; cy <= 2; ++cy) {
                #pragma unroll
                for (int cx = 1; cx <= 2; ++cx) {
                    const float c = dd[cy][cx];
                    #pragma unroll
                    for (int ny = -1; ny <= 1; ++ny) {
                        #pragma unroll
                        for (int nx = -1; nx <= 1; ++nx) {
                            if (ny == 0 && nx == 0) continue;
                            const float v = dd[cy + ny][cx + nx] - c;
                            sub += v * v;
                        }
                    }
                }
            }
            acc += act ? sub : 0.f;
        }
    };

    // ---- pipelined main loop: counted vmcnt, raw barriers ----
    stage(0, 0);
    stage(1, 1);
    for (int b = 0; b < NB; ++b) {
        if (b + 2 < NB) stage((b + 2) % NBUF, b + 2);
        if (b + 2 < NB)      asm volatile("s_waitcnt vmcnt(8)" ::: "memory");
        else if (b + 1 < NB) asm volatile("s_waitcnt vmcnt(4)" ::: "memory");
        else                 asm volatile("s_waitcnt vmcnt(0)" ::: "memory");
        asm volatile("s_barrier" ::: "memory");   // all waves' batch-b data in LDS
        compute(b % NBUF, b);
        asm volatile("s_barrier" ::: "memory");   // reads done before next overwrite
    }

    // ---- block reduction (fixed order, deterministic) ----
    #pragma unroll
    for (int off = 32; off; off >>= 1) acc += __shfl_down(acc, off, 64);
    if (lane == 0) red[wid] = acc;
    __syncthreads();
    if (t == 0) {
        partial[blockIdx.x] = red[0] + red[1] + red[2] + red[3];
        __threadfence();
    }

    // last arriving block reduces all partials in fixed order (R4-proven)
    __shared__ int is_last;
    if (t == 0) is_last = (atomicAdd(counter, 1) == (int)gridDim.x - 1) ? 1 : 0;
    __syncthreads();
    if (is_last) {
        __threadfence();
        float a = 0.f;
        const int nb = (int)gridDim.x;
        for (int i = t; i < nb; i += THREADS) a += partial[i];
        #pragma unroll
        for (int off = 32; off; off >>= 1) a += __shfl_down(a, off, 64);
        if (lane == 0) red[wid] = a;
        __syncthreads();
        if (t == 0) out[0] = (red[0] + red[1] + red[2] + red[3]) * inv_count;
    }
}

extern "C" void kernel_launch(void* const* d_in, const int* in_sizes, int n_in,
                              void* d_out, int out_size, void* d_ws, size_t ws_size,
                              hipStream_t stream) {
    const float* outp = (const float*)d_in[0];
    const float* labp = (const float*)d_in[1];
    const int nimg = in_sizes[0] / 1024;                      // B (H=W=32)
    const int nblocks = (nimg + NB * BI - 1) / (NB * BI);     // 2048 for B=16384
    const float inv_count = 1.0f / ((float)nimg * 8.0f * 900.0f);

    int* counter = (int*)d_ws;
    float* partial = (float*)d_ws + 64;
    hipMemsetAsync(counter, 0, sizeof(int), stream);          // graph-capture-safe

    cdl_fused<<<nblocks, THREADS, 0, stream>>>(outp, labp, partial, counter,
                                               (float*)d_out, nimg, inv_count);
}

// Round 8
// 28.918 us; speedup vs baseline: 2.9646x; 2.9646x over previous
//
#include <hip/hip_runtime.h>

// Contrast-depth loss:
//   d = out - label   (elementwise, [B,32,32] fp32)
//   loss = mean over (b, 8 neighbors, 30x30 centers) of
//          (d[y+dy][x+dx] - d[y][x])^2, centers y,x in [1,30]
//
// R8 design: per-thread 6x6-center tile (8x8 patch). 30=6*5 -> 25 tiles/image
// tile the 32x32 image EXACTLY (patch rows/cols 6k..6k+7, no masking, no OOB).
// L1 amplification 1.56x (vs 4x in R5). 64 independent immediate-offset 8B
// loads per thread; no LDS, no barriers, no shuffles. Deterministic 2-kernel
// reduction.

#define THREADS 256

__global__ __launch_bounds__(THREADS, 2) void cdl_partial(
    const float* __restrict__ outp,
    const float* __restrict__ labp,
    float* __restrict__ partial,
    int nimg)
{
    const int t  = threadIdx.x;
    const int tg = blockIdx.x * THREADS + t;
    const int img = tg / 25;                    // 25 tiles per image
    const int tau = tg - img * 25;
    const int ty = tau / 5, tx = tau - ty * 5;

    float a0 = 0.f, a1 = 0.f, a2 = 0.f, a3 = 0.f;

    if (img < nimg) {
        // patch origin: row 6ty, col 6tx (6tx even -> float2-aligned)
        const long long fb = (long long)img * 1024 + (6 * ty) * 32 + 6 * tx;
        const float2* ob = (const float2*)(outp + fb);
        const float2* lb = (const float2*)(labp + fb);

        // ---- 64 independent 8B loads, immediate offsets off two bases ----
        float2 ov[8][4], lv[8][4];
        #pragma unroll
        for (int r = 0; r < 8; ++r) {
            #pragma unroll
            for (int c = 0; c < 4; ++c) ov[r][c] = ob[r * 16 + c];
        }
        #pragma unroll
        for (int r = 0; r < 8; ++r) {
            #pragma unroll
            for (int c = 0; c < 4; ++c) lv[r][c] = lb[r * 16 + c];
        }

        // ---- subtract into 8x8 patch ----
        float d[8][8];
        #pragma unroll
        for (int r = 0; r < 8; ++r) {
            #pragma unroll
            for (int c = 0; c < 4; ++c) {
                d[r][2 * c]     = ov[r][c].x - lv[r][c].x;
                d[r][2 * c + 1] = ov[r][c].y - lv[r][c].y;
            }
        }

        // ---- 6x6 centers, 8 neighbors each; 4 rotating accumulators ----
        #pragma unroll
        for (int cy = 1; cy <= 6; ++cy) {
            #pragma unroll
            for (int cx = 1; cx <= 6; ++cx) {
                const float c = d[cy][cx];
                float s = 0.f, v;
                v = d[cy - 1][cx - 1] - c; s += v * v;
                v = d[cy - 1][cx    ] - c; s += v * v;
                v = d[cy - 1][cx + 1] - c; s += v * v;
                v = d[cy    ][cx - 1] - c; s += v * v;
                v = d[cy    ][cx + 1] - c; s += v * v;
                v = d[cy + 1][cx - 1] - c; s += v * v;
                v = d[cy + 1][cx    ] - c; s += v * v;
                v = d[cy + 1][cx + 1] - c; s += v * v;
                const int k = (cy * 6 + cx) & 3;
                if (k == 0) a0 += s; else if (k == 1) a1 += s;
                else if (k == 2) a2 += s; else a3 += s;
            }
        }
    }

    float acc = (a0 + a1) + (a2 + a3);

    // ---- block reduction (fixed order, deterministic) ----
    #pragma unroll
    for (int off = 32; off; off >>= 1) acc += __shfl_down(acc, off, 64);
    __shared__ float red[4];
    const int lane = t & 63, wid = t >> 6;
    if (lane == 0) red[wid] = acc;
    __syncthreads();
    if (t == 0) partial[blockIdx.x] = red[0] + red[1] + red[2] + red[3];
}

__global__ __launch_bounds__(THREADS) void cdl_final(
    const float* __restrict__ partial,
    float* __restrict__ out,
    int np,
    float inv_count)
{
    __shared__ float red[THREADS / 64];
    const int t = threadIdx.x;
    float acc = 0.f;
    for (int i = t; i < np; i += THREADS) acc += partial[i];
    #pragma unroll
    for (int off = 32; off; off >>= 1) acc += __shfl_down(acc, off, 64);
    if ((t & 63) == 0) red[t >> 6] = acc;
    __syncthreads();
    if (t == 0) out[0] = (red[0] + red[1] + red[2] + red[3]) * inv_count;
}

extern "C" void kernel_launch(void* const* d_in, const int* in_sizes, int n_in,
                              void* d_out, int out_size, void* d_ws, size_t ws_size,
                              hipStream_t stream) {
    const float* outp = (const float*)d_in[0];
    const float* labp = (const float*)d_in[1];
    float* partial = (float*)d_ws;
    const int nimg = in_sizes[0] / 1024;                       // B (H=W=32)
    const long long ntask = (long long)nimg * 25;
    const int nblocks = (int)((ntask + THREADS - 1) / THREADS); // 1600 for B=16384
    const float inv_count = 1.0f / ((float)nimg * 8.0f * 900.0f);

    cdl_partial<<<nblocks, THREADS, 0, stream>>>(outp, labp, partial, nimg);
    cdl_final<<<1, THREADS, 0, stream>>>(partial, (float*)d_out, nblocks, inv_count);
}